// Round 1
// baseline (1837.151 us; speedup 1.0000x reference)
//
#include <hip/hip_runtime.h>
#include <hip/hip_bf16.h>
#include <cstdint>
#include <math.h>

#define DEV static __device__ __forceinline__

typedef __attribute__((ext_vector_type(8))) __bf16 bf16x8v;
typedef __attribute__((ext_vector_type(4))) float f32x4;

constexpr int B = 4, T = 512, BT = B * T;
constexpr int D_MODEL = 769, D_INNER = 1538, D2 = 3076;
constexpr int DT_RANK = 49, D_STATE = 64, DBC = 177;  // 49 + 64 + 64
constexpr int NLAYER = 2;
// padded GEMM dims (K multiple of 64, N multiple of 128)
constexpr int KP_MODEL = 832;   // 769
constexpr int KP_INNER = 1600;  // 1538
constexpr int KP_DT    = 64;    // 49
constexpr int NP_IN  = 3200;    // 3076
constexpr int NP_X   = 256;     // 177
constexpr int NP_DT  = 1664;    // 1538
constexpr int NP_OUT = 896;     // 769

DEV float siluf(float v) { return v / (1.f + __expf(-v)); }

DEV float wredx(float v) {
#pragma unroll
  for (int o = 1; o < 64; o <<= 1) v += __shfl_xor(v, o);
  return v;
}

DEV void gload_lds16(const void* g, void* l) {
  __builtin_amdgcn_global_load_lds(
      (const __attribute__((address_space(1))) uint32_t*)(uintptr_t)g,
      (__attribute__((address_space(3))) uint32_t*)(uint32_t)(uintptr_t)l,
      16, 0, 0);
}

// ---------------- front end ----------------

// x (B,T,65) -> hp (B,128,T), silu(pointconv)
__global__ void front_pointconv(const float* __restrict__ x, const float* __restrict__ pw,
                                const float* __restrict__ pb, float* __restrict__ hp) {
  int t = blockIdx.x, b = blockIdx.y, c = threadIdx.x;
  __shared__ float xs[64];
  if (threadIdx.x < 64) xs[threadIdx.x] = x[((size_t)b * T + t) * 65 + threadIdx.x];
  __syncthreads();
  float acc = pb[c];
#pragma unroll
  for (int i = 0; i < 64; ++i) acc = fmaf(pw[c * 64 + i], xs[i], acc);
  hp[((size_t)b * 128 + c) * T + t] = siluf(acc);
}

// hp (B,128,T) -> h[:, :, co_off..co_off+256)  (SAME conv + silu), h is (B,T,769)
template <int K>
__global__ __launch_bounds__(256) void front_conv_k(const float* __restrict__ hp,
                                                    const float* __restrict__ W,
                                                    const float* __restrict__ bias,
                                                    float* __restrict__ h, int co_off) {
  constexpr int PAD = (K - 1) / 2;
  int b = blockIdx.y;
  int wid = threadIdx.x >> 6, lane = threadIdx.x & 63;
  int co = blockIdx.x * 4 + wid;
  int t0 = lane * 8;
  float bv = bias[co];
  float acc[8];
#pragma unroll
  for (int i = 0; i < 8; ++i) acc[i] = bv;
  const float* hpb = hp + (size_t)b * 128 * T;
  const float* wbase = W + (size_t)co * 128 * K;
  for (int ci = 0; ci < 128; ++ci) {
    const float* row = hpb + (size_t)ci * T;
    float win[8 + K - 1];
#pragma unroll
    for (int j = 0; j < 8 + K - 1; ++j) {
      int tt = t0 - PAD + j;
      win[j] = (tt >= 0 && tt < T) ? row[tt] : 0.f;
    }
    const float* wrow = wbase + ci * K;
#pragma unroll
    for (int k = 0; k < K; ++k) {
      float wv = wrow[k];
#pragma unroll
      for (int i = 0; i < 8; ++i) acc[i] = fmaf(wv, win[k + i], acc[i]);
    }
  }
  int c = co_off + co;
#pragma unroll
  for (int i = 0; i < 8; ++i)
    h[((size_t)b * T + t0 + i) * D_MODEL + c] = siluf(acc[i]);
}

__global__ void fill_pe(const float* __restrict__ x, float* __restrict__ h) {
  int i = blockIdx.x * 256 + threadIdx.x;
  if (i < BT) h[(size_t)i * D_MODEL + 768] = x[(size_t)i * 65 + 64];
}

// ---------------- helpers ----------------

// f32 (N,K) -> bf16 (Npad,Kpad) zero-padded
__global__ void cvt_pad(const float* __restrict__ src, __hip_bfloat16* __restrict__ dst,
                        int N, int K, int Npad, int Kpad) {
  int total = Npad * Kpad;
  for (int idx = blockIdx.x * 256 + threadIdx.x; idx < total; idx += gridDim.x * 256) {
    int n = idx / Kpad, k = idx - n * Kpad;
    float v = (n < N && k < K) ? src[(size_t)n * K + k] : 0.f;
    dst[idx] = __float2bfloat16(v);
  }
}

__global__ void zero_pad_cols(__hip_bfloat16* __restrict__ buf, int rows, int ld, int c0) {
  int w = ld - c0;
  int total = rows * w;
  int idx = blockIdx.x * 256 + threadIdx.x;
  if (idx < total) buf[(size_t)(idx / w) * ld + c0 + (idx % w)] = __float2bfloat16(0.f);
}

// rmsnorm row (769) -> bf16 padded row (832)
__global__ __launch_bounds__(256) void rmsnorm_bf(const float* __restrict__ h,
                                                  const float* __restrict__ w,
                                                  __hip_bfloat16* __restrict__ ubf) {
  int row = blockIdx.x;
  const float* hr = h + (size_t)row * D_MODEL;
  __shared__ float red[4];
  int wid = threadIdx.x >> 6, lane = threadIdx.x & 63;
  float ss = 0.f;
  for (int i = threadIdx.x; i < D_MODEL; i += 256) { float v = hr[i]; ss = fmaf(v, v, ss); }
  ss = wredx(ss);
  if (lane == 0) red[wid] = ss;
  __syncthreads();
  float tot = red[0] + red[1] + red[2] + red[3];
  float sc = rsqrtf(tot * (1.f / D_MODEL) + 1e-6f);
  for (int i = threadIdx.x; i < KP_MODEL; i += 256) {
    float v = (i < D_MODEL) ? hr[i] * sc * w[i] : 0.f;
    ubf[(size_t)row * KP_MODEL + i] = __float2bfloat16(v);
  }
}

// dbc (BT,177) cols<49 -> bf16 (BT,64) zero-padded
__global__ void cvt_dt_in(const float* __restrict__ dbc, __hip_bfloat16* __restrict__ dtbf) {
  int idx = blockIdx.x * 256 + threadIdx.x;
  if (idx >= BT * 64) return;
  int r = idx >> 6, c = idx & 63;
  float v = (c < DT_RANK) ? dbc[(size_t)r * DBC + c] : 0.f;
  dtbf[idx] = __float2bfloat16(v);
}

// ---------------- bf16 MFMA GEMM:  C[m][n] = sum_k A[m][k] * W[n][k] (+ epilogue) ----------------
// EPI 0: plain store; EPI 1: softplus(acc + bias[n]); EPI 2: acc + extra[m*ldadd+n]
template <int EPI>
__global__ __launch_bounds__(256) void gemm_bf16(const __hip_bfloat16* __restrict__ A,
                                                 const __hip_bfloat16* __restrict__ W,
                                                 float* __restrict__ C, int M, int Nreal, int Kp,
                                                 const float* extra, int ldadd) {
  __shared__ __align__(16) __hip_bfloat16 As[128 * 64];
  __shared__ __align__(16) __hip_bfloat16 Bs[128 * 64];
  const int tid = threadIdx.x;
  const int wid = tid >> 6, lane = tid & 63;
  const int wr = wid >> 1, wc = wid & 1;
  const int m0 = blockIdx.y * 128, n0 = blockIdx.x * 128;
  f32x4 acc[4][4] = {};
  const int lrow = lane >> 3;                                 // row within 8-row segment
  const int cbyte = ((lane & 7) << 4) ^ (lrow << 4);          // inverse-swizzled source col byte
  const char* Ab = (const char*)A;
  const char* Wb = (const char*)W;
  const size_t strideAB = (size_t)Kp * 2;
  const int swz = (lane & 7) << 4;

  for (int k0 = 0; k0 < Kp; k0 += 64) {
#pragma unroll
    for (int i = 0; i < 4; ++i) {
      int seg = i * 4 + wid;                                  // wave-uniform
      int row = seg * 8 + lrow;
      gload_lds16(Ab + (size_t)(m0 + row) * strideAB + k0 * 2 + cbyte, (char*)As + seg * 1024);
      gload_lds16(Wb + (size_t)(n0 + row) * strideAB + k0 * 2 + cbyte, (char*)Bs + seg * 1024);
    }
    __syncthreads();
#pragma unroll
    for (int kk = 0; kk < 2; ++kk) {
      int kb = kk * 64 + ((lane >> 4) << 4);                  // byte offset of this lane's 8 bf16
      bf16x8v af[4], bfr[4];
#pragma unroll
      for (int mi = 0; mi < 4; ++mi) {
        int row = wr * 64 + mi * 16 + (lane & 15);
        af[mi] = *(const bf16x8v*)((const char*)As + row * 128 + (kb ^ swz));
      }
#pragma unroll
      for (int ni = 0; ni < 4; ++ni) {
        int row = wc * 64 + ni * 16 + (lane & 15);
        bfr[ni] = *(const bf16x8v*)((const char*)Bs + row * 128 + (kb ^ swz));
      }
#pragma unroll
      for (int mi = 0; mi < 4; ++mi)
#pragma unroll
        for (int ni = 0; ni < 4; ++ni)
          acc[mi][ni] = __builtin_amdgcn_mfma_f32_16x16x32_bf16(af[mi], bfr[ni], acc[mi][ni], 0, 0, 0);
    }
    __syncthreads();
  }

#pragma unroll
  for (int mi = 0; mi < 4; ++mi) {
#pragma unroll
    for (int ni = 0; ni < 4; ++ni) {
      int n = n0 + wc * 64 + ni * 16 + (lane & 15);
      if (n < Nreal) {
        int mb = m0 + wr * 64 + mi * 16 + ((lane >> 4) << 2);
#pragma unroll
        for (int v = 0; v < 4; ++v) {
          float val = acc[mi][ni][v];
          int m = mb + v;
          if constexpr (EPI == 1) {
            val += extra[n];
            val = fmaxf(val, 0.f) + log1pf(__expf(-fabsf(val)));   // stable softplus
          } else if constexpr (EPI == 2) {
            val += extra[(size_t)m * ldadd + n];
          }
          C[(size_t)m * Nreal + n] = val;
        }
      }
    }
  }
}

// ---------------- depthwise causal conv (k=4) + silu ----------------
__global__ void dwconv_silu(const float* __restrict__ xz, const float* __restrict__ cw,
                            const float* __restrict__ cb, float* __restrict__ xin,
                            __hip_bfloat16* __restrict__ xinbf) {
  int idx = blockIdx.x * 256 + threadIdx.x;
  if (idx >= BT * D_INNER) return;
  int bt = idx / D_INNER;
  int d = idx - bt * D_INNER;
  int t = bt & (T - 1);
  float acc = cb[d];
  const float* col = xz + (size_t)bt * D2 + d;
#pragma unroll
  for (int k = 0; k < 4; ++k) {
    int tt = t + k - 3;
    float v = (tt >= 0) ? col[(ptrdiff_t)(k - 3) * D2] : 0.f;
    acc = fmaf(cw[d * 4 + k], v, acc);
  }
  acc = siluf(acc);
  xin[idx] = acc;
  xinbf[(size_t)bt * KP_INNER + d] = __float2bfloat16(acc);
}

// ---------------- selective scan + skip + gate, fused ----------------
// 2 states/lane, 32 n-groups, 2 d per wave; y reduced with shfl_xor over bits1..5
__global__ __launch_bounds__(256) void scan_gate(const float* __restrict__ xin,
                                                 const float* __restrict__ dtp,
                                                 const float* __restrict__ dbc,
                                                 const float* __restrict__ xz,
                                                 const float* __restrict__ A_log,
                                                 const float* __restrict__ Dskip,
                                                 __hip_bfloat16* __restrict__ ybf) {
  int b = blockIdx.y;
  int wid = threadIdx.x >> 6, lane = threadIdx.x & 63;
  int dwave = blockIdx.x * 8 + wid * 2;
  if (dwave >= D_INNER) return;              // wave-uniform exit
  int dl = lane & 1, ng = lane >> 1;
  int d = dwave + dl;
  int dc = (d < D_INNER) ? d : (D_INNER - 1);
  bool valid = (d < D_INNER);
  int nb = ng * 2;
  float a0 = -__expf(A_log[(size_t)dc * D_STATE + nb]);
  float a1 = -__expf(A_log[(size_t)dc * D_STATE + nb + 1]);
  float dsk = Dskip[dc];
  float h0 = 0.f, h1 = 0.f;
  const size_t rb = (size_t)b * T;
#pragma unroll 2
  for (int t = 0; t < T; ++t) {
    size_t r = rb + t;
    float dtv = dtp[r * D_INNER + dc];
    float du = xin[r * D_INNER + dc];
    const float* dr = dbc + r * DBC;
    float b0 = dr[DT_RANK + nb], b1 = dr[DT_RANK + nb + 1];
    float c0 = dr[DT_RANK + D_STATE + nb], c1 = dr[DT_RANK + D_STATE + nb + 1];
    float dtu = dtv * du;
    float e0 = __expf(dtv * a0), e1 = __expf(dtv * a1);
    h0 = fmaf(e0, h0, dtu * b0);
    h1 = fmaf(e1, h1, dtu * b1);
    float y = fmaf(h0, c0, h1 * c1);
#pragma unroll
    for (int off = 2; off < 64; off <<= 1) y += __shfl_xor(y, off);
    if (ng == 0 && valid) {
      float zv = xz[r * D2 + D_INNER + dc];
      float yo = (y + du * dsk) * siluf(zv);
      ybf[r * KP_INNER + dc] = __float2bfloat16(yo);
    }
  }
}

// ---------------- final layernorm + classifier ----------------
__global__ __launch_bounds__(256) void ln_head(const float* __restrict__ h,
                                               const float* __restrict__ lnw,
                                               const float* __restrict__ lnb,
                                               const float* __restrict__ ow,
                                               const float* __restrict__ ob,
                                               float* __restrict__ out) {
  int row = blockIdx.x;
  const float* hr = h + (size_t)row * D_MODEL;
  __shared__ float sh[D_MODEL];
  __shared__ float red[4];
  int wid = threadIdx.x >> 6, lane = threadIdx.x & 63;
  float s = 0.f;
  for (int i = threadIdx.x; i < D_MODEL; i += 256) { float v = hr[i]; sh[i] = v; s += v; }
  s = wredx(s);
  if (lane == 0) red[wid] = s;
  __syncthreads();
  float mean = (red[0] + red[1] + red[2] + red[3]) * (1.f / D_MODEL);
  __syncthreads();
  float vs = 0.f;
  for (int i = threadIdx.x; i < D_MODEL; i += 256) { float dd = sh[i] - mean; vs = fmaf(dd, dd, vs); }
  vs = wredx(vs);
  if (lane == 0) red[wid] = vs;
  __syncthreads();
  float var = (red[0] + red[1] + red[2] + red[3]) * (1.f / D_MODEL);
  float inv = rsqrtf(var + 1e-5f);
  for (int i = threadIdx.x; i < D_MODEL; i += 256)
    sh[i] = (sh[i] - mean) * inv * lnw[i] + lnb[i];
  __syncthreads();
  for (int c = wid; c < 10; c += 4) {
    float acc = 0.f;
    for (int i = lane; i < D_MODEL; i += 64) acc = fmaf(sh[i], ow[(size_t)c * D_MODEL + i], acc);
    acc = wredx(acc);
    if (lane == 0) out[(size_t)row * 10 + c] = acc + ob[c];
  }
}

// ---------------- launcher ----------------
extern "C" void kernel_launch(void* const* d_in, const int* in_sizes, int n_in,
                              void* d_out, int out_size, void* d_ws, size_t ws_size,
                              hipStream_t stream) {
  const float* x    = (const float*)d_in[0];
  const float* pcw  = (const float*)d_in[1];
  const float* pcb  = (const float*)d_in[2];
  const float* c1w  = (const float*)d_in[3];
  const float* c1b  = (const float*)d_in[4];
  const float* c2w  = (const float*)d_in[5];
  const float* c2b  = (const float*)d_in[6];
  const float* c3w  = (const float*)d_in[7];
  const float* c3b  = (const float*)d_in[8];
  const float* lnw  = (const float*)d_in[9];
  const float* lnb  = (const float*)d_in[10];
  const float* ow   = (const float*)d_in[11];
  const float* ob   = (const float*)d_in[12];
  const float* rmsw = (const float*)d_in[13];
  const float* Wi   = (const float*)d_in[14];
  const float* dww  = (const float*)d_in[15];
  const float* dwb  = (const float*)d_in[16];
  const float* Wx   = (const float*)d_in[17];
  const float* Wdt  = (const float*)d_in[18];
  const float* dtbv = (const float*)d_in[19];
  const float* Alog = (const float*)d_in[20];
  const float* Dsk  = (const float*)d_in[21];
  const float* Wo   = (const float*)d_in[22];
  float* out = (float*)d_out;

  char* w = (char*)d_ws;
  auto alloc = [&](size_t n) { char* p = w; w += (n + 255) & ~(size_t)255; return p; };
  float* hp            = (float*)alloc((size_t)B * 128 * T * 4);
  float* hbuf          = (float*)alloc((size_t)BT * D_MODEL * 4);
  __hip_bfloat16* ubf  = (__hip_bfloat16*)alloc((size_t)BT * KP_MODEL * 2);
  float* xz            = (float*)alloc((size_t)BT * D2 * 4);
  float* xin           = (float*)alloc((size_t)BT * D_INNER * 4);
  __hip_bfloat16* xinbf= (__hip_bfloat16*)alloc((size_t)BT * KP_INNER * 2);
  float* dbc           = (float*)alloc((size_t)BT * DBC * 4);
  __hip_bfloat16* dtbf = (__hip_bfloat16*)alloc((size_t)BT * KP_DT * 2);
  float* dtbuf         = (float*)alloc((size_t)BT * D_INNER * 4);
  __hip_bfloat16* ybf  = (__hip_bfloat16*)alloc((size_t)BT * KP_INNER * 2);
  __hip_bfloat16* Wibf = (__hip_bfloat16*)alloc((size_t)NP_IN * KP_MODEL * 2);
  __hip_bfloat16* Wxbf = (__hip_bfloat16*)alloc((size_t)NP_X * KP_INNER * 2);
  __hip_bfloat16* Wdtbf= (__hip_bfloat16*)alloc((size_t)NP_DT * KP_DT * 2);
  __hip_bfloat16* Wobf = (__hip_bfloat16*)alloc((size_t)NP_OUT * KP_INNER * 2);

  front_pointconv<<<dim3(T, B), 128, 0, stream>>>(x, pcw, pcb, hp);
  front_conv_k<3><<<dim3(64, B), 256, 0, stream>>>(hp, c1w, c1b, hbuf, 0);
  front_conv_k<9><<<dim3(64, B), 256, 0, stream>>>(hp, c2w, c2b, hbuf, 256);
  front_conv_k<27><<<dim3(64, B), 256, 0, stream>>>(hp, c3w, c3b, hbuf, 512);
  fill_pe<<<(BT + 255) / 256, 256, 0, stream>>>(x, hbuf);

  for (int l = 0; l < NLAYER; ++l) {
    cvt_pad<<<2048, 256, 0, stream>>>(Wi + (size_t)l * D2 * D_MODEL, Wibf, D2, D_MODEL, NP_IN, KP_MODEL);
    cvt_pad<<<512, 256, 0, stream>>>(Wx + (size_t)l * DBC * D_INNER, Wxbf, DBC, D_INNER, NP_X, KP_INNER);
    cvt_pad<<<256, 256, 0, stream>>>(Wdt + (size_t)l * D_INNER * DT_RANK, Wdtbf, D_INNER, DT_RANK, NP_DT, KP_DT);
    cvt_pad<<<1024, 256, 0, stream>>>(Wo + (size_t)l * D_MODEL * D_INNER, Wobf, D_MODEL, D_INNER, NP_OUT, KP_INNER);

    rmsnorm_bf<<<BT, 256, 0, stream>>>(hbuf, rmsw + (size_t)l * D_MODEL, ubf);
    gemm_bf16<0><<<dim3(NP_IN / 128, BT / 128), 256, 0, stream>>>(ubf, Wibf, xz, BT, D2, KP_MODEL, nullptr, 0);
    dwconv_silu<<<(BT * D_INNER + 255) / 256, 256, 0, stream>>>(xz, dww + (size_t)l * D_INNER * 4,
                                                                dwb + (size_t)l * D_INNER, xin, xinbf);
    zero_pad_cols<<<(BT * (KP_INNER - D_INNER) + 255) / 256, 256, 0, stream>>>(xinbf, BT, KP_INNER, D_INNER);
    gemm_bf16<0><<<dim3(NP_X / 128, BT / 128), 256, 0, stream>>>(xinbf, Wxbf, dbc, BT, DBC, KP_INNER, nullptr, 0);
    cvt_dt_in<<<(BT * 64 + 255) / 256, 256, 0, stream>>>(dbc, dtbf);
    gemm_bf16<1><<<dim3(NP_DT / 128, BT / 128), 256, 0, stream>>>(dtbf, Wdtbf, dtbuf, BT, D_INNER, KP_DT,
                                                                  dtbv + (size_t)l * D_INNER, 0);
    zero_pad_cols<<<(BT * (KP_INNER - D_INNER) + 255) / 256, 256, 0, stream>>>(ybf, BT, KP_INNER, D_INNER);
    scan_gate<<<dim3((D_INNER + 7) / 8, B), 256, 0, stream>>>(xin, dtbuf, dbc, xz,
                                                              Alog + (size_t)l * D_INNER * D_STATE,
                                                              Dsk + (size_t)l * D_INNER, ybf);
    gemm_bf16<2><<<dim3(NP_OUT / 128, BT / 128), 256, 0, stream>>>(ybf, Wobf, hbuf, BT, D_MODEL, KP_INNER,
                                                                   hbuf, D_MODEL);
  }
  ln_head<<<BT, 256, 0, stream>>>(hbuf, lnw, lnb, ow, ob, out);
}

// Round 2
// 1273.214 us; speedup vs baseline: 1.4429x; 1.4429x over previous
//
#include <hip/hip_runtime.h>
#include <hip/hip_bf16.h>
#include <cstdint>
#include <math.h>

#define DEV static __device__ __forceinline__

typedef __attribute__((ext_vector_type(8))) __bf16 bf16x8v;
typedef __attribute__((ext_vector_type(4))) float f32x4;

constexpr int B = 4, T = 512, BT = B * T;
constexpr int D_MODEL = 769, D_INNER = 1538, D2 = 3076;
constexpr int DT_RANK = 49, D_STATE = 64;
constexpr int LDBC = 192;       // padded dbc row: dt[0..49) | pad | B[64..128) | C[128..192)
constexpr int NLAYER = 2;
// padded GEMM dims (K multiple of 64, N multiple of 128)
constexpr int KP_MODEL = 832;   // 769
constexpr int KP_INNER = 1600;  // 1538
constexpr int KP_DT    = 64;    // 49
constexpr int NP_IN  = 3200;    // 3076
constexpr int NP_X   = 256;     // 177
constexpr int NP_DT  = 1664;    // 1538
constexpr int NP_OUT = 896;     // 769
constexpr int KCONV  = 3456;    // 27*128 unified front-conv reduction
constexpr int NCONV  = 768;

DEV float siluf(float v) { return v / (1.f + __expf(-v)); }

DEV float wredx(float v) {
#pragma unroll
  for (int o = 1; o < 64; o <<= 1) v += __shfl_xor(v, o);
  return v;
}

DEV void gload_lds16(const void* g, void* l) {
  __builtin_amdgcn_global_load_lds(
      (const __attribute__((address_space(1))) uint32_t*)(uintptr_t)g,
      (__attribute__((address_space(3))) uint32_t*)(uint32_t)(uintptr_t)l,
      16, 0, 0);
}

// ---------------- front end ----------------

// x (B,T,65) -> hpbf (B,T,128) = silu(pointconv), bf16
__global__ void front_pointconv(const float* __restrict__ x, const float* __restrict__ pw,
                                const float* __restrict__ pb, __hip_bfloat16* __restrict__ hpbf) {
  int t = blockIdx.x, b = blockIdx.y, c = threadIdx.x;  // 128 threads
  __shared__ float xs[64];
  if (c < 64) xs[c] = x[((size_t)b * T + t) * 65 + c];
  __syncthreads();
  float acc = pb[c];
  const float4* pwr = (const float4*)(pw + c * 64);
#pragma unroll
  for (int i = 0; i < 16; ++i) {
    float4 w4 = pwr[i];
    acc = fmaf(w4.x, xs[4 * i + 0], acc);
    acc = fmaf(w4.y, xs[4 * i + 1], acc);
    acc = fmaf(w4.z, xs[4 * i + 2], acc);
    acc = fmaf(w4.w, xs[4 * i + 3], acc);
  }
  hpbf[((size_t)b * T + t) * 128 + c] = __float2bfloat16(siluf(acc));
}

// hpbf (B,T,128) -> Xim (BT, 3456) bf16, col j*128+ci = hpbf[b, t-13+j, ci]
__global__ void im2col_front(const __hip_bfloat16* __restrict__ hpbf,
                             __hip_bfloat16* __restrict__ Xim) {
  int idx = blockIdx.x * 256 + threadIdx.x;  // BT*432 threads, 16B each
  if (idx >= BT * 432) return;
  int row = idx / 432, r = idx - row * 432;
  int j = r >> 4, seg = r & 15;
  int b = row >> 9, t = row & 511;
  int ts = t - 13 + j;
  uint4 v = {0u, 0u, 0u, 0u};
  if (ts >= 0 && ts < T) v = *(const uint4*)(hpbf + ((size_t)(b * T + ts)) * 128 + seg * 8);
  *(uint4*)(Xim + (size_t)row * KCONV + j * 128 + seg * 8) = v;
}

// c1w(256,128,3), c2w(256,128,9), c3w(256,128,27) -> Wfr(768, 3456) bf16
__global__ void build_conv_w(const float* __restrict__ c1w, const float* __restrict__ c2w,
                             const float* __restrict__ c3w, __hip_bfloat16* __restrict__ Wfr) {
  int total = NCONV * KCONV;
  for (int idx = blockIdx.x * 256 + threadIdx.x; idx < total; idx += gridDim.x * 256) {
    int co = idx / KCONV, r = idx - co * KCONV;
    int j = r >> 7, ci = r & 127;
    float v = 0.f;
    if (co < 256) {
      int k = j - 12;
      if (k >= 0 && k < 3) v = c1w[((size_t)co * 128 + ci) * 3 + k];
    } else if (co < 512) {
      int k = j - 9;
      if (k >= 0 && k < 9) v = c2w[((size_t)(co - 256) * 128 + ci) * 9 + k];
    } else {
      v = c3w[((size_t)(co - 512) * 128 + ci) * 27 + j];
    }
    Wfr[idx] = __float2bfloat16(v);
  }
}

__global__ void build_conv_b(const float* __restrict__ b1, const float* __restrict__ b2,
                             const float* __restrict__ b3, float* __restrict__ cb) {
  int i = blockIdx.x * 256 + threadIdx.x;
  if (i >= NCONV) return;
  cb[i] = (i < 256) ? b1[i] : (i < 512) ? b2[i - 256] : b3[i - 512];
}

__global__ void fill_pe(const float* __restrict__ x, float* __restrict__ h) {
  int i = blockIdx.x * 256 + threadIdx.x;
  if (i < BT) h[(size_t)i * D_MODEL + 768] = x[(size_t)i * 65 + 64];
}

// ---------------- helpers ----------------

// f32 (N,K) -> bf16 (Npad,Kpad) zero-padded
__global__ void cvt_pad(const float* __restrict__ src, __hip_bfloat16* __restrict__ dst,
                        int N, int K, int Npad, int Kpad) {
  int total = Npad * Kpad;
  for (int idx = blockIdx.x * 256 + threadIdx.x; idx < total; idx += gridDim.x * 256) {
    int n = idx / Kpad, k = idx - n * Kpad;
    float v = (n < N && k < K) ? src[(size_t)n * K + k] : 0.f;
    dst[idx] = __float2bfloat16(v);
  }
}

__global__ void zero_pad_cols(__hip_bfloat16* __restrict__ buf, int rows, int ld, int c0) {
  int w = ld - c0;
  int total = rows * w;
  int idx = blockIdx.x * 256 + threadIdx.x;
  if (idx < total) buf[(size_t)(idx / w) * ld + c0 + (idx % w)] = __float2bfloat16(0.f);
}

// rmsnorm row (769) -> bf16 padded row (832)
__global__ __launch_bounds__(256) void rmsnorm_bf(const float* __restrict__ h,
                                                  const float* __restrict__ w,
                                                  __hip_bfloat16* __restrict__ ubf) {
  int row = blockIdx.x;
  const float* hr = h + (size_t)row * D_MODEL;
  __shared__ float red[4];
  int wid = threadIdx.x >> 6, lane = threadIdx.x & 63;
  float ss = 0.f;
  for (int i = threadIdx.x; i < D_MODEL; i += 256) { float v = hr[i]; ss = fmaf(v, v, ss); }
  ss = wredx(ss);
  if (lane == 0) red[wid] = ss;
  __syncthreads();
  float tot = red[0] + red[1] + red[2] + red[3];
  float sc = rsqrtf(tot * (1.f / D_MODEL) + 1e-6f);
  for (int i = threadIdx.x; i < KP_MODEL; i += 256) {
    float v = (i < D_MODEL) ? hr[i] * sc * w[i] : 0.f;
    ubf[(size_t)row * KP_MODEL + i] = __float2bfloat16(v);
  }
}

// dbc (BT,192) cols<49 -> bf16 (BT,64) zero-padded
__global__ void cvt_dt_in(const float* __restrict__ dbc, __hip_bfloat16* __restrict__ dtbf) {
  int idx = blockIdx.x * 256 + threadIdx.x;
  if (idx >= BT * 64) return;
  int r = idx >> 6, c = idx & 63;
  float v = (c < DT_RANK) ? dbc[(size_t)r * LDBC + c] : 0.f;
  dtbf[idx] = __float2bfloat16(v);
}

// ---------------- bf16 MFMA GEMM:  C[m][n] = sum_k A[m][k] * W[n][k] (+ epilogue) ----------------
// EPI 0: plain; 1: softplus(acc+bias[n]); 2: acc+extra[m*ldadd+n]; 3: silu(acc+bias[n]); 4: dbc col remap
template <int EPI>
__global__ __launch_bounds__(256) void gemm_bf16(const __hip_bfloat16* __restrict__ A,
                                                 const __hip_bfloat16* __restrict__ W,
                                                 float* __restrict__ C, int M, int Nreal, int Kp,
                                                 const float* extra, int ldadd, int ldc) {
  __shared__ __align__(16) __hip_bfloat16 As[128 * 64];
  __shared__ __align__(16) __hip_bfloat16 Bs[128 * 64];
  const int tid = threadIdx.x;
  const int wid = tid >> 6, lane = tid & 63;
  const int wr = wid >> 1, wc = wid & 1;
  const int m0 = blockIdx.y * 128, n0 = blockIdx.x * 128;
  f32x4 acc[4][4] = {};
  const int lrow = lane >> 3;                                 // row within 8-row segment
  const int cbyte = ((lane & 7) << 4) ^ (lrow << 4);          // inverse-swizzled source col byte
  const char* Ab = (const char*)A;
  const char* Wb = (const char*)W;
  const size_t strideAB = (size_t)Kp * 2;
  const int swz = (lane & 7) << 4;

  for (int k0 = 0; k0 < Kp; k0 += 64) {
#pragma unroll
    for (int i = 0; i < 4; ++i) {
      int seg = i * 4 + wid;                                  // wave-uniform
      int row = seg * 8 + lrow;
      gload_lds16(Ab + (size_t)(m0 + row) * strideAB + k0 * 2 + cbyte, (char*)As + seg * 1024);
      gload_lds16(Wb + (size_t)(n0 + row) * strideAB + k0 * 2 + cbyte, (char*)Bs + seg * 1024);
    }
    __syncthreads();
#pragma unroll
    for (int kk = 0; kk < 2; ++kk) {
      int kb = kk * 64 + ((lane >> 4) << 4);                  // byte offset of this lane's 8 bf16
      bf16x8v af[4], bfr[4];
#pragma unroll
      for (int mi = 0; mi < 4; ++mi) {
        int row = wr * 64 + mi * 16 + (lane & 15);
        af[mi] = *(const bf16x8v*)((const char*)As + row * 128 + (kb ^ swz));
      }
#pragma unroll
      for (int ni = 0; ni < 4; ++ni) {
        int row = wc * 64 + ni * 16 + (lane & 15);
        bfr[ni] = *(const bf16x8v*)((const char*)Bs + row * 128 + (kb ^ swz));
      }
#pragma unroll
      for (int mi = 0; mi < 4; ++mi)
#pragma unroll
        for (int ni = 0; ni < 4; ++ni)
          acc[mi][ni] = __builtin_amdgcn_mfma_f32_16x16x32_bf16(af[mi], bfr[ni], acc[mi][ni], 0, 0, 0);
    }
    __syncthreads();
  }

#pragma unroll
  for (int mi = 0; mi < 4; ++mi) {
#pragma unroll
    for (int ni = 0; ni < 4; ++ni) {
      int n = n0 + wc * 64 + ni * 16 + (lane & 15);
      if (n < Nreal) {
        int nout = n;
        if constexpr (EPI == 4) nout = (n < DT_RANK) ? n : n + 15;
        int mb = m0 + wr * 64 + mi * 16 + ((lane >> 4) << 2);
#pragma unroll
        for (int v = 0; v < 4; ++v) {
          float val = acc[mi][ni][v];
          int m = mb + v;
          if constexpr (EPI == 1) {
            val += extra[n];
            val = fmaxf(val, 0.f) + log1pf(__expf(-fabsf(val)));   // stable softplus
          } else if constexpr (EPI == 2) {
            val += extra[(size_t)m * ldadd + n];
          } else if constexpr (EPI == 3) {
            val = siluf(val + extra[n]);
          }
          C[(size_t)m * ldc + nout] = val;
        }
      }
    }
  }
}

// ---------------- depthwise causal conv (k=4) + silu ----------------
__global__ void dwconv_silu(const float* __restrict__ xz, const float* __restrict__ cw,
                            const float* __restrict__ cb, float* __restrict__ xin,
                            __hip_bfloat16* __restrict__ xinbf) {
  int idx = blockIdx.x * 256 + threadIdx.x;
  if (idx >= BT * D_INNER) return;
  int bt = idx / D_INNER;
  int d = idx - bt * D_INNER;
  int t = bt & (T - 1);
  float acc = cb[d];
  const float* col = xz + (size_t)bt * D2 + d;
#pragma unroll
  for (int k = 0; k < 4; ++k) {
    int tt = t + k - 3;
    float v = (tt >= 0) ? col[(ptrdiff_t)(k - 3) * D2] : 0.f;
    acc = fmaf(cw[d * 4 + k], v, acc);
  }
  acc = siluf(acc);
  xin[idx] = acc;
  xinbf[(size_t)bt * KP_INNER + d] = __float2bfloat16(acc);
}

// ---------------- selective scan + skip + gate, fused ----------------
__global__ __launch_bounds__(256) void scan_gate(const float* __restrict__ xin,
                                                 const float* __restrict__ dtp,
                                                 const float* __restrict__ dbc,
                                                 const float* __restrict__ xz,
                                                 const float* __restrict__ A_log,
                                                 const float* __restrict__ Dskip,
                                                 __hip_bfloat16* __restrict__ ybf) {
  int b = blockIdx.y;
  int wid = threadIdx.x >> 6, lane = threadIdx.x & 63;
  int dwave = blockIdx.x * 8 + wid * 2;
  if (dwave >= D_INNER) return;              // wave-uniform exit
  int dl = lane & 1, ng = lane >> 1;
  int d = dwave + dl;
  int dc = (d < D_INNER) ? d : (D_INNER - 1);
  bool valid = (d < D_INNER);
  int nb = ng * 2;
  float a0 = -__expf(A_log[(size_t)dc * D_STATE + nb]);
  float a1 = -__expf(A_log[(size_t)dc * D_STATE + nb + 1]);
  float dsk = Dskip[dc];
  float h0 = 0.f, h1 = 0.f;
  const size_t rb = (size_t)b * T;
#pragma unroll 2
  for (int t = 0; t < T; ++t) {
    size_t r = rb + t;
    float dtv = dtp[r * D_INNER + dc];
    float du = xin[r * D_INNER + dc];
    const float* dr = dbc + r * LDBC;
    float2 bb = *(const float2*)(dr + 64 + nb);
    float2 cc = *(const float2*)(dr + 128 + nb);
    float dtu = dtv * du;
    float e0 = __expf(dtv * a0), e1 = __expf(dtv * a1);
    h0 = fmaf(e0, h0, dtu * bb.x);
    h1 = fmaf(e1, h1, dtu * bb.y);
    float y = fmaf(h0, cc.x, h1 * cc.y);
#pragma unroll
    for (int off = 2; off < 64; off <<= 1) y += __shfl_xor(y, off);
    if (ng == 0 && valid) {
      float zv = xz[r * D2 + D_INNER + dc];
      float yo = (y + du * dsk) * siluf(zv);
      ybf[r * KP_INNER + dc] = __float2bfloat16(yo);
    }
  }
}

// ---------------- final layernorm + classifier ----------------
__global__ __launch_bounds__(256) void ln_head(const float* __restrict__ h,
                                               const float* __restrict__ lnw,
                                               const float* __restrict__ lnb,
                                               const float* __restrict__ ow,
                                               const float* __restrict__ ob,
                                               float* __restrict__ out) {
  int row = blockIdx.x;
  const float* hr = h + (size_t)row * D_MODEL;
  __shared__ float sh[D_MODEL];
  __shared__ float red[4];
  int wid = threadIdx.x >> 6, lane = threadIdx.x & 63;
  float s = 0.f;
  for (int i = threadIdx.x; i < D_MODEL; i += 256) { float v = hr[i]; sh[i] = v; s += v; }
  s = wredx(s);
  if (lane == 0) red[wid] = s;
  __syncthreads();
  float mean = (red[0] + red[1] + red[2] + red[3]) * (1.f / D_MODEL);
  __syncthreads();
  float vs = 0.f;
  for (int i = threadIdx.x; i < D_MODEL; i += 256) { float dd = sh[i] - mean; vs = fmaf(dd, dd, vs); }
  vs = wredx(vs);
  if (lane == 0) red[wid] = vs;
  __syncthreads();
  float var = (red[0] + red[1] + red[2] + red[3]) * (1.f / D_MODEL);
  float inv = rsqrtf(var + 1e-5f);
  for (int i = threadIdx.x; i < D_MODEL; i += 256)
    sh[i] = (sh[i] - mean) * inv * lnw[i] + lnb[i];
  __syncthreads();
  for (int c = wid; c < 10; c += 4) {
    float acc = 0.f;
    for (int i = lane; i < D_MODEL; i += 64) acc = fmaf(sh[i], ow[(size_t)c * D_MODEL + i], acc);
    acc = wredx(acc);
    if (lane == 0) out[(size_t)row * 10 + c] = acc + ob[c];
  }
}

// ---------------- launcher ----------------
extern "C" void kernel_launch(void* const* d_in, const int* in_sizes, int n_in,
                              void* d_out, int out_size, void* d_ws, size_t ws_size,
                              hipStream_t stream) {
  const float* x    = (const float*)d_in[0];
  const float* pcw  = (const float*)d_in[1];
  const float* pcb  = (const float*)d_in[2];
  const float* c1w  = (const float*)d_in[3];
  const float* c1b  = (const float*)d_in[4];
  const float* c2w  = (const float*)d_in[5];
  const float* c2b  = (const float*)d_in[6];
  const float* c3w  = (const float*)d_in[7];
  const float* c3b  = (const float*)d_in[8];
  const float* lnw  = (const float*)d_in[9];
  const float* lnb  = (const float*)d_in[10];
  const float* ow   = (const float*)d_in[11];
  const float* ob   = (const float*)d_in[12];
  const float* rmsw = (const float*)d_in[13];
  const float* Wi   = (const float*)d_in[14];
  const float* dww  = (const float*)d_in[15];
  const float* dwb  = (const float*)d_in[16];
  const float* Wx   = (const float*)d_in[17];
  const float* Wdt  = (const float*)d_in[18];
  const float* dtbv = (const float*)d_in[19];
  const float* Alog = (const float*)d_in[20];
  const float* Dsk  = (const float*)d_in[21];
  const float* Wo   = (const float*)d_in[22];
  float* out = (float*)d_out;

  char* w = (char*)d_ws;
  auto alloc = [&](size_t n) { char* p = w; w += (n + 255) & ~(size_t)255; return p; };
  float* hbuf          = (float*)alloc((size_t)BT * D_MODEL * 4);
  __hip_bfloat16* hpbf = (__hip_bfloat16*)alloc((size_t)BT * 128 * 2);
  __hip_bfloat16* Xim  = (__hip_bfloat16*)alloc((size_t)BT * KCONV * 2);
  __hip_bfloat16* Wfr  = (__hip_bfloat16*)alloc((size_t)NCONV * KCONV * 2);
  float* cb768         = (float*)alloc((size_t)NCONV * 4);
  __hip_bfloat16* ubf  = (__hip_bfloat16*)alloc((size_t)BT * KP_MODEL * 2);
  float* xz            = (float*)alloc((size_t)BT * D2 * 4);
  float* xin           = (float*)alloc((size_t)BT * D_INNER * 4);
  __hip_bfloat16* xinbf= (__hip_bfloat16*)alloc((size_t)BT * KP_INNER * 2);
  float* dbc           = (float*)alloc((size_t)BT * LDBC * 4);
  __hip_bfloat16* dtbf = (__hip_bfloat16*)alloc((size_t)BT * KP_DT * 2);
  float* dtbuf         = (float*)alloc((size_t)BT * D_INNER * 4);
  __hip_bfloat16* ybf  = (__hip_bfloat16*)alloc((size_t)BT * KP_INNER * 2);
  __hip_bfloat16* Wibf = (__hip_bfloat16*)alloc((size_t)NP_IN * KP_MODEL * 2);
  __hip_bfloat16* Wxbf = (__hip_bfloat16*)alloc((size_t)NP_X * KP_INNER * 2);
  __hip_bfloat16* Wdtbf= (__hip_bfloat16*)alloc((size_t)NP_DT * KP_DT * 2);
  __hip_bfloat16* Wobf = (__hip_bfloat16*)alloc((size_t)NP_OUT * KP_INNER * 2);

  front_pointconv<<<dim3(T, B), 128, 0, stream>>>(x, pcw, pcb, hpbf);
  im2col_front<<<(BT * 432) / 256, 256, 0, stream>>>(hpbf, Xim);
  build_conv_w<<<2048, 256, 0, stream>>>(c1w, c2w, c3w, Wfr);
  build_conv_b<<<3, 256, 0, stream>>>(c1b, c2b, c3b, cb768);
  gemm_bf16<3><<<dim3(NCONV / 128, BT / 128), 256, 0, stream>>>(Xim, Wfr, hbuf, BT, NCONV, KCONV,
                                                                cb768, 0, D_MODEL);
  fill_pe<<<(BT + 255) / 256, 256, 0, stream>>>(x, hbuf);

  for (int l = 0; l < NLAYER; ++l) {
    cvt_pad<<<2048, 256, 0, stream>>>(Wi + (size_t)l * D2 * D_MODEL, Wibf, D2, D_MODEL, NP_IN, KP_MODEL);
    cvt_pad<<<512, 256, 0, stream>>>(Wx + (size_t)l * (DT_RANK + 2 * D_STATE) * D_INNER, Wxbf,
                                     DT_RANK + 2 * D_STATE, D_INNER, NP_X, KP_INNER);
    cvt_pad<<<256, 256, 0, stream>>>(Wdt + (size_t)l * D_INNER * DT_RANK, Wdtbf, D_INNER, DT_RANK, NP_DT, KP_DT);
    cvt_pad<<<1024, 256, 0, stream>>>(Wo + (size_t)l * D_MODEL * D_INNER, Wobf, D_MODEL, D_INNER, NP_OUT, KP_INNER);

    rmsnorm_bf<<<BT, 256, 0, stream>>>(hbuf, rmsw + (size_t)l * D_MODEL, ubf);
    gemm_bf16<0><<<dim3(NP_IN / 128, BT / 128), 256, 0, stream>>>(ubf, Wibf, xz, BT, D2, KP_MODEL,
                                                                  nullptr, 0, D2);
    dwconv_silu<<<(BT * D_INNER + 255) / 256, 256, 0, stream>>>(xz, dww + (size_t)l * D_INNER * 4,
                                                                dwb + (size_t)l * D_INNER, xin, xinbf);
    zero_pad_cols<<<(BT * (KP_INNER - D_INNER) + 255) / 256, 256, 0, stream>>>(xinbf, BT, KP_INNER, D_INNER);
    gemm_bf16<4><<<dim3(NP_X / 128, BT / 128), 256, 0, stream>>>(xinbf, Wxbf, dbc, BT,
                                                                 DT_RANK + 2 * D_STATE, KP_INNER,
                                                                 nullptr, 0, LDBC);
    cvt_dt_in<<<(BT * 64 + 255) / 256, 256, 0, stream>>>(dbc, dtbf);
    gemm_bf16<1><<<dim3(NP_DT / 128, BT / 128), 256, 0, stream>>>(dtbf, Wdtbf, dtbuf, BT, D_INNER, KP_DT,
                                                                  dtbv + (size_t)l * D_INNER, 0, D_INNER);
    zero_pad_cols<<<(BT * (KP_INNER - D_INNER) + 255) / 256, 256, 0, stream>>>(ybf, BT, KP_INNER, D_INNER);
    scan_gate<<<dim3((D_INNER + 7) / 8, B), 256, 0, stream>>>(xin, dtbuf, dbc, xz,
                                                              Alog + (size_t)l * D_INNER * D_STATE,
                                                              Dsk + (size_t)l * D_INNER, ybf);
    gemm_bf16<2><<<dim3(NP_OUT / 128, BT / 128), 256, 0, stream>>>(ybf, Wobf, hbuf, BT, D_MODEL, KP_INNER,
                                                                   hbuf, D_MODEL, D_MODEL);
  }
  ln_head<<<BT, 256, 0, stream>>>(hbuf, lnw, lnb, ow, ob, out);
}

// Round 3
// 764.289 us; speedup vs baseline: 2.4037x; 1.6659x over previous
//
#include <hip/hip_runtime.h>
#include <hip/hip_bf16.h>
#include <cstdint>
#include <math.h>

#define DEV static __device__ __forceinline__

typedef __attribute__((ext_vector_type(8))) __bf16 bf16x8v;
typedef __attribute__((ext_vector_type(4))) float f32x4;

constexpr int B = 4, T = 512, BT = B * T;
constexpr int D_MODEL = 769, D_INNER = 1538, D2 = 3076;
constexpr int DT_RANK = 49, D_STATE = 64;
constexpr int LDBC = 192;       // padded dbc row: dt[0..49) | pad | B[64..128) | C[128..192)
constexpr int NLAYER = 2;
// padded GEMM dims (K multiple of 64, N multiple of 128)
constexpr int KP_MODEL = 832;   // 769
constexpr int KP_INNER = 1600;  // 1538
constexpr int KP_DT    = 64;    // 49
constexpr int NP_IN  = 3200;    // 3076
constexpr int NP_X   = 256;     // 177
constexpr int NP_DT  = 1664;    // 1538
constexpr int NP_OUT = 896;     // 769
constexpr int KCONV  = 3456;    // 27*128 unified front-conv reduction
constexpr int NCONV  = 768;

DEV float siluf(float v) { return v / (1.f + __expf(-v)); }

DEV float wredx(float v) {
#pragma unroll
  for (int o = 1; o < 64; o <<= 1) v += __shfl_xor(v, o);
  return v;
}

DEV void gload_lds16(const void* g, void* l) {
  __builtin_amdgcn_global_load_lds(
      (const __attribute__((address_space(1))) uint32_t*)(uintptr_t)g,
      (__attribute__((address_space(3))) uint32_t*)(uint32_t)(uintptr_t)l,
      16, 0, 0);
}

// ---------------- front end ----------------

// x (B,T,65) -> hpbf (B,T,128) = silu(pointconv), bf16
__global__ void front_pointconv(const float* __restrict__ x, const float* __restrict__ pw,
                                const float* __restrict__ pb, __hip_bfloat16* __restrict__ hpbf) {
  int t = blockIdx.x, b = blockIdx.y, c = threadIdx.x;  // 128 threads
  __shared__ float xs[64];
  if (c < 64) xs[c] = x[((size_t)b * T + t) * 65 + c];
  __syncthreads();
  float acc = pb[c];
  const float4* pwr = (const float4*)(pw + c * 64);
#pragma unroll
  for (int i = 0; i < 16; ++i) {
    float4 w4 = pwr[i];
    acc = fmaf(w4.x, xs[4 * i + 0], acc);
    acc = fmaf(w4.y, xs[4 * i + 1], acc);
    acc = fmaf(w4.z, xs[4 * i + 2], acc);
    acc = fmaf(w4.w, xs[4 * i + 3], acc);
  }
  hpbf[((size_t)b * T + t) * 128 + c] = __float2bfloat16(siluf(acc));
}

// hpbf (B,T,128) -> Xim (BT, 3456) bf16, col j*128+ci = hpbf[b, t-13+j, ci]
__global__ void im2col_front(const __hip_bfloat16* __restrict__ hpbf,
                             __hip_bfloat16* __restrict__ Xim) {
  int idx = blockIdx.x * 256 + threadIdx.x;  // BT*432 threads, 16B each
  if (idx >= BT * 432) return;
  int row = idx / 432, r = idx - row * 432;
  int j = r >> 4, seg = r & 15;
  int b = row >> 9, t = row & 511;
  int ts = t - 13 + j;
  uint4 v = {0u, 0u, 0u, 0u};
  if (ts >= 0 && ts < T) v = *(const uint4*)(hpbf + ((size_t)(b * T + ts)) * 128 + seg * 8);
  *(uint4*)(Xim + (size_t)row * KCONV + j * 128 + seg * 8) = v;
}

// c1w(256,128,3), c2w(256,128,9), c3w(256,128,27) -> Wfr(768, 3456) bf16
__global__ void build_conv_w(const float* __restrict__ c1w, const float* __restrict__ c2w,
                             const float* __restrict__ c3w, __hip_bfloat16* __restrict__ Wfr) {
  int total = NCONV * KCONV;
  for (int idx = blockIdx.x * 256 + threadIdx.x; idx < total; idx += gridDim.x * 256) {
    int co = idx / KCONV, r = idx - co * KCONV;
    int j = r >> 7, ci = r & 127;
    float v = 0.f;
    if (co < 256) {
      int k = j - 12;
      if (k >= 0 && k < 3) v = c1w[((size_t)co * 128 + ci) * 3 + k];
    } else if (co < 512) {
      int k = j - 9;
      if (k >= 0 && k < 9) v = c2w[((size_t)(co - 256) * 128 + ci) * 9 + k];
    } else {
      v = c3w[((size_t)(co - 512) * 128 + ci) * 27 + j];
    }
    Wfr[idx] = __float2bfloat16(v);
  }
}

__global__ void build_conv_b(const float* __restrict__ b1, const float* __restrict__ b2,
                             const float* __restrict__ b3, float* __restrict__ cb) {
  int i = blockIdx.x * 256 + threadIdx.x;
  if (i >= NCONV) return;
  cb[i] = (i < 256) ? b1[i] : (i < 512) ? b2[i - 256] : b3[i - 512];
}

__global__ void fill_pe(const float* __restrict__ x, float* __restrict__ h) {
  int i = blockIdx.x * 256 + threadIdx.x;
  if (i < BT) h[(size_t)i * D_MODEL + 768] = x[(size_t)i * 65 + 64];
}

// ---------------- helpers ----------------

// f32 (N,K) -> bf16 (Npad,Kpad) zero-padded
__global__ void cvt_pad(const float* __restrict__ src, __hip_bfloat16* __restrict__ dst,
                        int N, int K, int Npad, int Kpad) {
  int total = Npad * Kpad;
  for (int idx = blockIdx.x * 256 + threadIdx.x; idx < total; idx += gridDim.x * 256) {
    int n = idx / Kpad, k = idx - n * Kpad;
    float v = (n < N && k < K) ? src[(size_t)n * K + k] : 0.f;
    dst[idx] = __float2bfloat16(v);
  }
}

__global__ void zero_pad_cols(__hip_bfloat16* __restrict__ buf, int rows, int ld, int c0) {
  int w = ld - c0;
  int total = rows * w;
  int idx = blockIdx.x * 256 + threadIdx.x;
  if (idx < total) buf[(size_t)(idx / w) * ld + c0 + (idx % w)] = __float2bfloat16(0.f);
}

// rmsnorm row (769) -> bf16 padded row (832)
__global__ __launch_bounds__(256) void rmsnorm_bf(const float* __restrict__ h,
                                                  const float* __restrict__ w,
                                                  __hip_bfloat16* __restrict__ ubf) {
  int row = blockIdx.x;
  const float* hr = h + (size_t)row * D_MODEL;
  __shared__ float red[4];
  int wid = threadIdx.x >> 6, lane = threadIdx.x & 63;
  float ss = 0.f;
  for (int i = threadIdx.x; i < D_MODEL; i += 256) { float v = hr[i]; ss = fmaf(v, v, ss); }
  ss = wredx(ss);
  if (lane == 0) red[wid] = ss;
  __syncthreads();
  float tot = red[0] + red[1] + red[2] + red[3];
  float sc = rsqrtf(tot * (1.f / D_MODEL) + 1e-6f);
  for (int i = threadIdx.x; i < KP_MODEL; i += 256) {
    float v = (i < D_MODEL) ? hr[i] * sc * w[i] : 0.f;
    ubf[(size_t)row * KP_MODEL + i] = __float2bfloat16(v);
  }
}

// dbc (BT,192) cols<49 -> bf16 (BT,64) zero-padded
__global__ void cvt_dt_in(const float* __restrict__ dbc, __hip_bfloat16* __restrict__ dtbf) {
  int idx = blockIdx.x * 256 + threadIdx.x;
  if (idx >= BT * 64) return;
  int r = idx >> 6, c = idx & 63;
  float v = (c < DT_RANK) ? dbc[(size_t)r * LDBC + c] : 0.f;
  dtbf[idx] = __float2bfloat16(v);
}

// ---------------- bf16 MFMA GEMM:  C[m][n] = sum_k A[m][k] * W[n][k] (+ epilogue) ----------------
// EPI 0: plain; 1: softplus(acc+bias[n]); 2: acc+extra[m*ldadd+n]; 3: silu(acc+bias[n]); 4: dbc col remap
template <int EPI>
__global__ __launch_bounds__(256) void gemm_bf16(const __hip_bfloat16* __restrict__ A,
                                                 const __hip_bfloat16* __restrict__ W,
                                                 float* __restrict__ C, int M, int Nreal, int Kp,
                                                 const float* extra, int ldadd, int ldc) {
  __shared__ __align__(16) __hip_bfloat16 As[128 * 64];
  __shared__ __align__(16) __hip_bfloat16 Bs[128 * 64];
  const int tid = threadIdx.x;
  const int wid = tid >> 6, lane = tid & 63;
  const int wr = wid >> 1, wc = wid & 1;
  const int m0 = blockIdx.y * 128, n0 = blockIdx.x * 128;
  f32x4 acc[4][4] = {};
  const int lrow = lane >> 3;                                 // row within 8-row segment
  const int cbyte = ((lane & 7) << 4) ^ (lrow << 4);          // inverse-swizzled source col byte
  const char* Ab = (const char*)A;
  const char* Wb = (const char*)W;
  const size_t strideAB = (size_t)Kp * 2;
  const int swz = (lane & 7) << 4;

  for (int k0 = 0; k0 < Kp; k0 += 64) {
#pragma unroll
    for (int i = 0; i < 4; ++i) {
      int seg = i * 4 + wid;                                  // wave-uniform
      int row = seg * 8 + lrow;
      gload_lds16(Ab + (size_t)(m0 + row) * strideAB + k0 * 2 + cbyte, (char*)As + seg * 1024);
      gload_lds16(Wb + (size_t)(n0 + row) * strideAB + k0 * 2 + cbyte, (char*)Bs + seg * 1024);
    }
    __syncthreads();
#pragma unroll
    for (int kk = 0; kk < 2; ++kk) {
      int kb = kk * 64 + ((lane >> 4) << 4);                  // byte offset of this lane's 8 bf16
      bf16x8v af[4], bfr[4];
#pragma unroll
      for (int mi = 0; mi < 4; ++mi) {
        int row = wr * 64 + mi * 16 + (lane & 15);
        af[mi] = *(const bf16x8v*)((const char*)As + row * 128 + (kb ^ swz));
      }
#pragma unroll
      for (int ni = 0; ni < 4; ++ni) {
        int row = wc * 64 + ni * 16 + (lane & 15);
        bfr[ni] = *(const bf16x8v*)((const char*)Bs + row * 128 + (kb ^ swz));
      }
#pragma unroll
      for (int mi = 0; mi < 4; ++mi)
#pragma unroll
        for (int ni = 0; ni < 4; ++ni)
          acc[mi][ni] = __builtin_amdgcn_mfma_f32_16x16x32_bf16(af[mi], bfr[ni], acc[mi][ni], 0, 0, 0);
    }
    __syncthreads();
  }

#pragma unroll
  for (int mi = 0; mi < 4; ++mi) {
#pragma unroll
    for (int ni = 0; ni < 4; ++ni) {
      int n = n0 + wc * 64 + ni * 16 + (lane & 15);
      if (n < Nreal) {
        int nout = n;
        if constexpr (EPI == 4) nout = (n < DT_RANK) ? n : n + 15;
        int mb = m0 + wr * 64 + mi * 16 + ((lane >> 4) << 2);
#pragma unroll
        for (int v = 0; v < 4; ++v) {
          float val = acc[mi][ni][v];
          int m = mb + v;
          if constexpr (EPI == 1) {
            val += extra[n];
            val = fmaxf(val, 0.f) + log1pf(__expf(-fabsf(val)));   // stable softplus
          } else if constexpr (EPI == 2) {
            val += extra[(size_t)m * ldadd + n];
          } else if constexpr (EPI == 3) {
            val = siluf(val + extra[n]);
          }
          C[(size_t)m * ldc + nout] = val;
        }
      }
    }
  }
}

// ---------------- depthwise causal conv (k=4) + silu ----------------
__global__ void dwconv_silu(const float* __restrict__ xz, const float* __restrict__ cw,
                            const float* __restrict__ cb, float* __restrict__ xin,
                            __hip_bfloat16* __restrict__ xinbf) {
  int idx = blockIdx.x * 256 + threadIdx.x;
  if (idx >= BT * D_INNER) return;
  int bt = idx / D_INNER;
  int d = idx - bt * D_INNER;
  int t = bt & (T - 1);
  float acc = cb[d];
  const float* col = xz + (size_t)bt * D2 + d;
#pragma unroll
  for (int k = 0; k < 4; ++k) {
    int tt = t + k - 3;
    float v = (tt >= 0) ? col[(ptrdiff_t)(k - 3) * D2] : 0.f;
    acc = fmaf(cw[d * 4 + k], v, acc);
  }
  acc = siluf(acc);
  xin[idx] = acc;
  xinbf[(size_t)bt * KP_INNER + d] = __float2bfloat16(acc);
}

// ---------------- selective scan + skip + gate, fused ----------------
// 1 wave per (b,d): 64 states in 64 lanes; register double-buffered chunks of 8 t;
// batched butterfly reduction (10 shuffles per 8 t); lane l<8 stores t0+l.
#define LOAD_CHUNK(Bv, Cv, DTv, DUv, DUs, ZVs, T0)                         \
  {                                                                         \
    _Pragma("unroll") for (int k = 0; k < 8; ++k) {                         \
      size_t r = rb + (T0) + k;                                             \
      Bv[k] = dbc[r * LDBC + 64 + lane];                                    \
      Cv[k] = dbc[r * LDBC + 128 + lane];                                   \
      DTv[k] = dtp[r * D_INNER + dc];                                       \
      DUv[k] = xin[r * D_INNER + dc];                                       \
    }                                                                       \
    size_t rs = rb + (T0) + (lane & 7);                                     \
    DUs = xin[rs * D_INNER + dc];                                           \
    ZVs = xz[rs * D2 + D_INNER + dc];                                       \
  }

#define COMPUTE_CHUNK(Bv, Cv, DTv, DUv, DUs, ZVs, T0)                       \
  {                                                                         \
    float vv[8];                                                            \
    _Pragma("unroll") for (int k = 0; k < 8; ++k) {                         \
      float e = exp2f(DTv[k] * a2);                                         \
      h = fmaf(e, h, DTv[k] * DUv[k] * Bv[k]);                              \
      vv[k] = h * Cv[k];                                                    \
    }                                                                       \
    _Pragma("unroll") for (int k = 0; k < 4; ++k) {                         \
      float snd = bb2 ? vv[k] : vv[k + 4];                                  \
      float kp = bb2 ? vv[k + 4] : vv[k];                                   \
      vv[k] = kp + __shfl_xor(snd, 4);                                      \
    }                                                                       \
    _Pragma("unroll") for (int k = 0; k < 2; ++k) {                         \
      float snd = bb1 ? vv[k] : vv[k + 2];                                  \
      float kp = bb1 ? vv[k + 2] : vv[k];                                   \
      vv[k] = kp + __shfl_xor(snd, 2);                                      \
    }                                                                       \
    {                                                                       \
      float snd = bb0 ? vv[0] : vv[1];                                      \
      float kp = bb0 ? vv[1] : vv[0];                                       \
      vv[0] = kp + __shfl_xor(snd, 1);                                      \
    }                                                                       \
    float y = vv[0];                                                        \
    y += __shfl_xor(y, 8);                                                  \
    y += __shfl_xor(y, 16);                                                 \
    y += __shfl_xor(y, 32);                                                 \
    if (valid && lane < 8) {                                                \
      float yo = (y + DUs * dsk) * siluf(ZVs);                              \
      ybf[(rb + (T0) + lane) * KP_INNER + dc] = __float2bfloat16(yo);       \
    }                                                                       \
  }

__global__ __launch_bounds__(256) void scan_gate(const float* __restrict__ xin,
                                                 const float* __restrict__ dtp,
                                                 const float* __restrict__ dbc,
                                                 const float* __restrict__ xz,
                                                 const float* __restrict__ A_log,
                                                 const float* __restrict__ Dskip,
                                                 __hip_bfloat16* __restrict__ ybf) {
  int b = blockIdx.y;
  int wid = threadIdx.x >> 6, lane = threadIdx.x & 63;
  int d = blockIdx.x * 4 + wid;
  bool valid = (d < D_INNER);
  int dc = valid ? d : (D_INNER - 1);
  const bool bb2 = lane & 4, bb1 = lane & 2, bb0 = lane & 1;
  float a2 = -__expf(A_log[(size_t)dc * D_STATE + lane]) * 1.44269504f;
  float dsk = Dskip[dc];
  float h = 0.f;
  const size_t rb = (size_t)b * T;

  float Ba[8], Ca[8], dta[8], dua[8], dusA, zvsA;
  float Bb[8], Cb[8], dtb[8], dub[8], dusB, zvsB;
  LOAD_CHUNK(Ba, Ca, dta, dua, dusA, zvsA, 0);
  for (int t0 = 0; t0 < T; t0 += 16) {
    LOAD_CHUNK(Bb, Cb, dtb, dub, dusB, zvsB, t0 + 8);
    COMPUTE_CHUNK(Ba, Ca, dta, dua, dusA, zvsA, t0);
    if (t0 + 16 < T) LOAD_CHUNK(Ba, Ca, dta, dua, dusA, zvsA, t0 + 16);
    COMPUTE_CHUNK(Bb, Cb, dtb, dub, dusB, zvsB, t0 + 8);
  }
}

// ---------------- final layernorm + classifier ----------------
__global__ __launch_bounds__(256) void ln_head(const float* __restrict__ h,
                                               const float* __restrict__ lnw,
                                               const float* __restrict__ lnb,
                                               const float* __restrict__ ow,
                                               const float* __restrict__ ob,
                                               float* __restrict__ out) {
  int row = blockIdx.x;
  const float* hr = h + (size_t)row * D_MODEL;
  __shared__ float sh[D_MODEL];
  __shared__ float red[4];
  int wid = threadIdx.x >> 6, lane = threadIdx.x & 63;
  float s = 0.f;
  for (int i = threadIdx.x; i < D_MODEL; i += 256) { float v = hr[i]; sh[i] = v; s += v; }
  s = wredx(s);
  if (lane == 0) red[wid] = s;
  __syncthreads();
  float mean = (red[0] + red[1] + red[2] + red[3]) * (1.f / D_MODEL);
  __syncthreads();
  float vs = 0.f;
  for (int i = threadIdx.x; i < D_MODEL; i += 256) { float dd = sh[i] - mean; vs = fmaf(dd, dd, vs); }
  vs = wredx(vs);
  if (lane == 0) red[wid] = vs;
  __syncthreads();
  float var = (red[0] + red[1] + red[2] + red[3]) * (1.f / D_MODEL);
  float inv = rsqrtf(var + 1e-5f);
  for (int i = threadIdx.x; i < D_MODEL; i += 256)
    sh[i] = (sh[i] - mean) * inv * lnw[i] + lnb[i];
  __syncthreads();
  for (int c = wid; c < 10; c += 4) {
    float acc = 0.f;
    for (int i = lane; i < D_MODEL; i += 64) acc = fmaf(sh[i], ow[(size_t)c * D_MODEL + i], acc);
    acc = wredx(acc);
    if (lane == 0) out[(size_t)row * 10 + c] = acc + ob[c];
  }
}

// ---------------- launcher ----------------
extern "C" void kernel_launch(void* const* d_in, const int* in_sizes, int n_in,
                              void* d_out, int out_size, void* d_ws, size_t ws_size,
                              hipStream_t stream) {
  const float* x    = (const float*)d_in[0];
  const float* pcw  = (const float*)d_in[1];
  const float* pcb  = (const float*)d_in[2];
  const float* c1w  = (const float*)d_in[3];
  const float* c1b  = (const float*)d_in[4];
  const float* c2w  = (const float*)d_in[5];
  const float* c2b  = (const float*)d_in[6];
  const float* c3w  = (const float*)d_in[7];
  const float* c3b  = (const float*)d_in[8];
  const float* lnw  = (const float*)d_in[9];
  const float* lnb  = (const float*)d_in[10];
  const float* ow   = (const float*)d_in[11];
  const float* ob   = (const float*)d_in[12];
  const float* rmsw = (const float*)d_in[13];
  const float* Wi   = (const float*)d_in[14];
  const float* dww  = (const float*)d_in[15];
  const float* dwb  = (const float*)d_in[16];
  const float* Wx   = (const float*)d_in[17];
  const float* Wdt  = (const float*)d_in[18];
  const float* dtbv = (const float*)d_in[19];
  const float* Alog = (const float*)d_in[20];
  const float* Dsk  = (const float*)d_in[21];
  const float* Wo   = (const float*)d_in[22];
  float* out = (float*)d_out;

  char* w = (char*)d_ws;
  auto alloc = [&](size_t n) { char* p = w; w += (n + 255) & ~(size_t)255; return p; };
  float* hbuf          = (float*)alloc((size_t)BT * D_MODEL * 4);
  __hip_bfloat16* hpbf = (__hip_bfloat16*)alloc((size_t)BT * 128 * 2);
  __hip_bfloat16* Xim  = (__hip_bfloat16*)alloc((size_t)BT * KCONV * 2);
  __hip_bfloat16* Wfr  = (__hip_bfloat16*)alloc((size_t)NCONV * KCONV * 2);
  float* cb768         = (float*)alloc((size_t)NCONV * 4);
  __hip_bfloat16* ubf  = (__hip_bfloat16*)alloc((size_t)BT * KP_MODEL * 2);
  float* xz            = (float*)alloc((size_t)BT * D2 * 4);
  float* xin           = (float*)alloc((size_t)BT * D_INNER * 4);
  __hip_bfloat16* xinbf= (__hip_bfloat16*)alloc((size_t)BT * KP_INNER * 2);
  float* dbc           = (float*)alloc((size_t)BT * LDBC * 4);
  __hip_bfloat16* dtbf = (__hip_bfloat16*)alloc((size_t)BT * KP_DT * 2);
  float* dtbuf         = (float*)alloc((size_t)BT * D_INNER * 4);
  __hip_bfloat16* ybf  = (__hip_bfloat16*)alloc((size_t)BT * KP_INNER * 2);
  __hip_bfloat16* Wibf = (__hip_bfloat16*)alloc((size_t)NP_IN * KP_MODEL * 2);
  __hip_bfloat16* Wxbf = (__hip_bfloat16*)alloc((size_t)NP_X * KP_INNER * 2);
  __hip_bfloat16* Wdtbf= (__hip_bfloat16*)alloc((size_t)NP_DT * KP_DT * 2);
  __hip_bfloat16* Wobf = (__hip_bfloat16*)alloc((size_t)NP_OUT * KP_INNER * 2);

  front_pointconv<<<dim3(T, B), 128, 0, stream>>>(x, pcw, pcb, hpbf);
  im2col_front<<<(BT * 432) / 256, 256, 0, stream>>>(hpbf, Xim);
  build_conv_w<<<2048, 256, 0, stream>>>(c1w, c2w, c3w, Wfr);
  build_conv_b<<<3, 256, 0, stream>>>(c1b, c2b, c3b, cb768);
  gemm_bf16<3><<<dim3(NCONV / 128, BT / 128), 256, 0, stream>>>(Xim, Wfr, hbuf, BT, NCONV, KCONV,
                                                                cb768, 0, D_MODEL);
  fill_pe<<<(BT + 255) / 256, 256, 0, stream>>>(x, hbuf);

  for (int l = 0; l < NLAYER; ++l) {
    cvt_pad<<<2048, 256, 0, stream>>>(Wi + (size_t)l * D2 * D_MODEL, Wibf, D2, D_MODEL, NP_IN, KP_MODEL);
    cvt_pad<<<512, 256, 0, stream>>>(Wx + (size_t)l * (DT_RANK + 2 * D_STATE) * D_INNER, Wxbf,
                                     DT_RANK + 2 * D_STATE, D_INNER, NP_X, KP_INNER);
    cvt_pad<<<256, 256, 0, stream>>>(Wdt + (size_t)l * D_INNER * DT_RANK, Wdtbf, D_INNER, DT_RANK, NP_DT, KP_DT);
    cvt_pad<<<1024, 256, 0, stream>>>(Wo + (size_t)l * D_MODEL * D_INNER, Wobf, D_MODEL, D_INNER, NP_OUT, KP_INNER);

    rmsnorm_bf<<<BT, 256, 0, stream>>>(hbuf, rmsw + (size_t)l * D_MODEL, ubf);
    gemm_bf16<0><<<dim3(NP_IN / 128, BT / 128), 256, 0, stream>>>(ubf, Wibf, xz, BT, D2, KP_MODEL,
                                                                  nullptr, 0, D2);
    dwconv_silu<<<(BT * D_INNER + 255) / 256, 256, 0, stream>>>(xz, dww + (size_t)l * D_INNER * 4,
                                                                dwb + (size_t)l * D_INNER, xin, xinbf);
    zero_pad_cols<<<(BT * (KP_INNER - D_INNER) + 255) / 256, 256, 0, stream>>>(xinbf, BT, KP_INNER, D_INNER);
    gemm_bf16<4><<<dim3(NP_X / 128, BT / 128), 256, 0, stream>>>(xinbf, Wxbf, dbc, BT,
                                                                 DT_RANK + 2 * D_STATE, KP_INNER,
                                                                 nullptr, 0, LDBC);
    cvt_dt_in<<<(BT * 64 + 255) / 256, 256, 0, stream>>>(dbc, dtbf);
    gemm_bf16<1><<<dim3(NP_DT / 128, BT / 128), 256, 0, stream>>>(dtbf, Wdtbf, dtbuf, BT, D_INNER, KP_DT,
                                                                  dtbv + (size_t)l * D_INNER, 0, D_INNER);
    zero_pad_cols<<<(BT * (KP_INNER - D_INNER) + 255) / 256, 256, 0, stream>>>(ybf, BT, KP_INNER, D_INNER);
    scan_gate<<<dim3((D_INNER + 3) / 4, B), 256, 0, stream>>>(xin, dtbuf, dbc, xz,
                                                              Alog + (size_t)l * D_INNER * D_STATE,
                                                              Dsk + (size_t)l * D_INNER, ybf);
    gemm_bf16<2><<<dim3(NP_OUT / 128, BT / 128), 256, 0, stream>>>(ybf, Wobf, hbuf, BT, D_MODEL, KP_INNER,
                                                                   hbuf, D_MODEL, D_MODEL);
  }
  ln_head<<<BT, 256, 0, stream>>>(hbuf, lnw, lnb, ow, ob, out);
}